// Round 21
// baseline (78.353 us; speedup 1.0000x reference)
//
#include <hip/hip_runtime.h>

#define N_NODES 50000
#define N_EDGES 800000
#define D_FEAT  64
#define TOTALSD (N_NODES * D_FEAT)       // 3,200,000 elems per plane

#define BKT_SHIFT 6
#define NB  782                          // ceil(50000/64) buckets of 64 nodes
#define C_SCAT 4096
#define NCHUNK_SCAT ((N_EDGES + C_SCAT - 1) / C_SCAT)   // 196
#define NPACK ((TOTALSD + 4095) / 4096)                 // 782 pack WGs
#define CAP 2048

typedef float nfloat2 __attribute__((ext_vector_type(2)));
typedef float nfloat4 __attribute__((ext_vector_type(4)));
typedef unsigned int nuint2 __attribute__((ext_vector_type(2)));

// ---------------- bf16/8B workspace layout (bytes) ----------------
#define WSB_GCUR  0
#define WSB_NOFF  4096
#define WSB_NEND  204160
#define WSB_SBF   404224
#define WSB_RECS  13204224
#define CSG_MIN   1216                   // >= 6 sigma above realized max bucket

// ---------------- f32 fixed-segment layout (R18 proven fallback) ----------------
#define WSF_GCUR  0
#define WSF_NOFF  4096
#define WSF_NEND  204160
#define WSF_RECS  404224

// ---- exclusive scan of NB(=782) ints with 256 threads (ends with sync) ----
__device__ __forceinline__ void scan_nb(const int* __restrict__ cnt,
                                        int* __restrict__ off) {
    __shared__ int wsum2[4];
    const int tid = threadIdx.x, lane = tid & 63, wid = tid >> 6;
    const int i0 = tid * 4;
    int v[4]; int s = 0;
    #pragma unroll
    for (int j = 0; j < 4; ++j) { v[j] = (i0 + j < NB) ? cnt[i0 + j] : 0; s += v[j]; }
    int x = s;
    #pragma unroll
    for (int k = 1; k < 64; k <<= 1) { int t = __shfl_up(x, k, 64); if (lane >= k) x += t; }
    if (lane == 63) wsum2[wid] = x;
    __syncthreads();
    int wpre = 0;
    for (int k = 0; k < wid; ++k) wpre += wsum2[k];
    int pre = wpre + x - s;
    #pragma unroll
    for (int j = 0; j < 4; ++j) { if (i0 + j < NB) off[i0 + j] = pre; pre += v[j]; }
    if (tid == 255) off[NB] = pre;
    __syncthreads();
}

__device__ __forceinline__ unsigned int bf16rne(float f) {
    unsigned int u = __float_as_uint(f);
    return (u + 0x7fffu + ((u >> 16) & 1u)) >> 16;
}

// ======== fused build: blocks [0,196) scatter 8B records; [196,978) pack state ========
__global__ __launch_bounds__(256) void build_fused(const int* __restrict__ ei,
                                                   const float* __restrict__ w,
                                                   const float* __restrict__ state,
                                                   int* __restrict__ gcur,
                                                   nuint2* __restrict__ recs8,
                                                   unsigned int* __restrict__ sbf,
                                                   const int csg) {
    __shared__ int cnt[NB];
    __shared__ int off[NB + 1];
    __shared__ int run[NB];
    __shared__ int gpos[NB];
    __shared__ int seid[C_SCAT];
    const int tid = threadIdx.x;

    if (blockIdx.x >= NCHUNK_SCAT) {
        // ---- pack branch: 4096 elems per WG, uint4 stores ----
        const int base0 = (blockIdx.x - NCHUNK_SCAT) * 4096;
        #pragma unroll
        for (int k = 0; k < 4; ++k) {
            const int idx = base0 + k * 1024 + tid * 4;
            if (idx < TOTALSD) {
                const nfloat4 a = *(const nfloat4*)(state + idx);
                const nfloat4 b = *(const nfloat4*)(state + (size_t)TOTALSD + idx);
                uint4 o;
                o.x = bf16rne(a.x) | (bf16rne(b.x) << 16);
                o.y = bf16rne(a.y) | (bf16rne(b.y) << 16);
                o.z = bf16rne(a.z) | (bf16rne(b.z) << 16);
                o.w = bf16rne(a.w) | (bf16rne(b.w) << 16);
                *(uint4*)(sbf + idx) = o;
            }
        }
        return;
    }

    // ---- scatter branch (control flow identical to validated R18 scatter_fix) ----
    const int base = blockIdx.x * C_SCAT;
    const int csz  = min(C_SCAT, N_EDGES - base);

    for (int i = tid; i < NB; i += 256) cnt[i] = 0;
    __syncthreads();
    for (int k = 0; k < C_SCAT / 256; ++k) {
        const int p = k * 256 + tid;
        if (p < csz) atomicAdd(&cnt[ei[N_EDGES + base + p] >> BKT_SHIFT], 1);
    }
    __syncthreads();
    scan_nb(cnt, off);
    for (int i = tid; i < NB; i += 256) run[i] = off[i];
    __syncthreads();
    for (int i = tid; i < NB; i += 256) {
        const int c = off[i + 1] - off[i];
        gpos[i] = c ? (i * csg + atomicAdd(&gcur[i], c) - off[i]) : 0;
    }
    for (int k = 0; k < C_SCAT / 256; ++k) {
        const int p = k * 256 + tid;
        if (p < csz) {
            const int r = atomicAdd(&run[ei[N_EDGES + base + p] >> BKT_SHIFT], 1);
            seid[r] = p;
        }
    }
    __syncthreads();
    for (int k = 0; k < C_SCAT / 256; ++k) {
        const int p = k * 256 + tid;
        if (p < csz) {
            const int e   = base + seid[p];
            const int dst = ei[N_EDGES + e];
            const int b   = dst >> BKT_SHIFT;
            const int slot = gpos[b] + p;
            if (slot - b * csg < csg) {                   // overflow guard
                const nfloat2 wv = *(const nfloat2*)(w + 2 * (size_t)e);
                nuint2 rec;
                rec.x = ((unsigned int)ei[e] << 6) | (unsigned int)(dst & 63);
                rec.y = bf16rne(wv.x) | (bf16rne(wv.y) << 16);
                recs8[(size_t)slot] = rec;
            }
        }
    }
}

// sort: per-bucket in-place node sort of 8B records; emits [nodeoff, nodeend)
__global__ __launch_bounds__(256) void sort_fix8(const int* __restrict__ gcur,
                                                 nuint2* __restrict__ recs8,
                                                 int* __restrict__ nodeoff,
                                                 int* __restrict__ nodeend,
                                                 const int csg) {
    __shared__ nuint2 srecs[CAP];        // 16 KB
    __shared__ int cnt64[64];
    __shared__ int run64[64];
    const int tid = threadIdx.x;
    const int b = blockIdx.x;
    const int node0 = b << BKT_SHIFT;
    const int j0 = b * csg;
    const int cnt = min(gcur[b], csg);

    if (gcur[b] > csg) {                 // unreachable for this input; stay defined
        if (tid < 64 && node0 + tid < N_NODES) {
            nodeoff[node0 + tid] = -1;
            nodeend[node0 + tid] = -1;
        }
        return;
    }
    if (tid < 64) cnt64[tid] = 0;
    __syncthreads();
    for (int p = tid; p < cnt; p += 256) {
        const nuint2 r = recs8[j0 + p];
        srecs[p] = r;
        atomicAdd(&cnt64[r.x & 63u], 1);
    }
    __syncthreads();
    if (tid < 64) {
        const int v = cnt64[tid];
        int x = v;
        #pragma unroll
        for (int k = 1; k < 64; k <<= 1) { int t = __shfl_up(x, k, 64); if (tid >= k) x += t; }
        run64[tid] = x - v;
        if (node0 + tid < N_NODES) {
            nodeoff[node0 + tid] = j0 + x - v;
            nodeend[node0 + tid] = j0 + x;
        }
    }
    __syncthreads();
    for (int p = tid; p < cnt; p += 256) {
        const nuint2 r = srecs[p];
        const int rk = atomicAdd(&run64[r.x & 63u], 1);
        recs8[j0 + rk] = r;
    }
}

// gather: scalar-pipe record broadcast (uniform s_load), 16 sbf loads in flight.
__global__ __launch_bounds__(256) void gather_bf8(const unsigned int* __restrict__ sbf,
                                                  const int* __restrict__ nodeoff,
                                                  const int* __restrict__ nodeend,
                                                  const int* __restrict__ gcur,
                                                  const nuint2* __restrict__ recs8,
                                                  float* __restrict__ out,
                                                  const int csg) {
    const int n = blockIdx.x * 4 + (threadIdx.x >> 6);
    const int d = threadIdx.x & 63;
    if (n >= N_NODES) return;
    const size_t plane = (size_t)N_NODES * D_FEAT;

    const int j0 = nodeoff[n];
    float a0 = 0.f, a1 = 0.f;
    if (j0 < 0) {
        // oversized-bucket slow path (unreachable): filter-scan the segment
        const int b = n >> BKT_SHIFT;
        const int node0 = b << BKT_SHIFT;
        const int jb0 = b * csg, jb1 = jb0 + min(gcur[b], csg);
        for (int j = jb0; j < jb1; ++j) {
            const nuint2 r = recs8[j];
            if ((int)(node0 + (r.x & 63u)) == n) {
                const int s = (int)(r.x >> 6);
                const unsigned int v = sbf[(size_t)s * D_FEAT + d];
                a0 += __uint_as_float(v << 16)         * __uint_as_float(r.y << 16);
                a1 += __uint_as_float(v & 0xffff0000u) * __uint_as_float(r.y & 0xffff0000u);
            }
        }
    } else {
        // wave-uniform bounds -> scalar pipe for record loads (no shfl, no LDS)
        const int j0u = __builtin_amdgcn_readfirstlane(j0);
        const int j1u = __builtin_amdgcn_readfirstlane(nodeend[n]);

        int j = j0u;
        for (; j + 16 <= j1u; j += 16) {
            unsigned int rx[16], ry[16], v[16];
            #pragma unroll
            for (int u = 0; u < 16; ++u) {
                const nuint2 r = recs8[j + u];    // uniform addr -> s_load/broadcast
                rx[u] = r.x; ry[u] = r.y;
            }
            #pragma unroll
            for (int u = 0; u < 16; ++u)
                v[u] = sbf[(size_t)(rx[u] >> 6) * D_FEAT + d];
            #pragma unroll
            for (int u = 0; u < 16; ++u) {
                a0 += __uint_as_float(v[u] << 16)         * __uint_as_float(ry[u] << 16);
                a1 += __uint_as_float(v[u] & 0xffff0000u) * __uint_as_float(ry[u] & 0xffff0000u);
            }
        }
        if (j < j1u) {
            // masked 16-group tail: uniform clamp-index + zero-weight keeps MLP
            unsigned int rx[16], ry[16], v[16];
            #pragma unroll
            for (int u = 0; u < 16; ++u) {
                const int jj = (j + u < j1u) ? (j + u) : j0u;   // safe, written slot
                const nuint2 r = recs8[jj];
                rx[u] = r.x;
                ry[u] = (j + u < j1u) ? r.y : 0u;               // zero weight kills pad
            }
            #pragma unroll
            for (int u = 0; u < 16; ++u)
                v[u] = sbf[(size_t)(rx[u] >> 6) * D_FEAT + d];
            #pragma unroll
            for (int u = 0; u < 16; ++u) {
                a0 += __uint_as_float(v[u] << 16)         * __uint_as_float(ry[u] << 16);
                a1 += __uint_as_float(v[u] & 0xffff0000u) * __uint_as_float(ry[u] & 0xffff0000u);
            }
        }
    }
    __builtin_nontemporal_store(a0, out + (size_t)n * D_FEAT + d);
    __builtin_nontemporal_store(a1, out + plane + (size_t)n * D_FEAT + d);
}

// ================= f32 fixed-segment pipeline (R18 proven fallback) =================
__global__ __launch_bounds__(256) void scatter_fix(const int* __restrict__ ei,
                                                   const float* __restrict__ w,
                                                   int* __restrict__ gcur,
                                                   nfloat4* __restrict__ recs,
                                                   const int csg) {
    __shared__ int cnt[NB];
    __shared__ int off[NB + 1];
    __shared__ int run[NB];
    __shared__ int gpos[NB];
    __shared__ int seid[C_SCAT];
    const int tid  = threadIdx.x;
    const int base = blockIdx.x * C_SCAT;
    const int csz  = min(C_SCAT, N_EDGES - base);

    for (int i = tid; i < NB; i += 256) cnt[i] = 0;
    __syncthreads();
    for (int k = 0; k < C_SCAT / 256; ++k) {
        const int p = k * 256 + tid;
        if (p < csz) atomicAdd(&cnt[ei[N_EDGES + base + p] >> BKT_SHIFT], 1);
    }
    __syncthreads();
    scan_nb(cnt, off);
    for (int i = tid; i < NB; i += 256) run[i] = off[i];
    __syncthreads();
    for (int i = tid; i < NB; i += 256) {
        const int c = off[i + 1] - off[i];
        gpos[i] = c ? (i * csg + atomicAdd(&gcur[i], c) - off[i]) : 0;
    }
    for (int k = 0; k < C_SCAT / 256; ++k) {
        const int p = k * 256 + tid;
        if (p < csz) {
            const int r = atomicAdd(&run[ei[N_EDGES + base + p] >> BKT_SHIFT], 1);
            seid[r] = p;
        }
    }
    __syncthreads();
    for (int k = 0; k < C_SCAT / 256; ++k) {
        const int p = k * 256 + tid;
        if (p < csz) {
            const int e   = base + seid[p];
            const int dst = ei[N_EDGES + e];
            const int b   = dst >> BKT_SHIFT;
            const int slot = gpos[b] + p;
            if (slot - b * csg < csg) {
                const nfloat2 wv = *(const nfloat2*)(w + 2 * (size_t)e);
                nfloat4 rec;
                rec.x = __int_as_float(ei[e]);
                rec.y = wv.x;
                rec.z = wv.y;
                rec.w = __int_as_float(dst);
                recs[(size_t)slot] = rec;
            }
        }
    }
}

__global__ __launch_bounds__(256) void sort_fix(const int* __restrict__ gcur,
                                                nfloat4* __restrict__ recs,
                                                int* __restrict__ nodeoff,
                                                int* __restrict__ nodeend,
                                                const int csg) {
    __shared__ nfloat4 srecs[CAP];
    __shared__ int cnt64[64];
    __shared__ int run64[64];
    const int tid = threadIdx.x;
    const int b = blockIdx.x;
    const int node0 = b << BKT_SHIFT;
    const int j0 = b * csg;
    const int cnt = min(gcur[b], csg);

    if (gcur[b] > csg) {
        if (tid < 64 && node0 + tid < N_NODES) {
            nodeoff[node0 + tid] = -1;
            nodeend[node0 + tid] = -1;
        }
        return;
    }
    if (tid < 64) cnt64[tid] = 0;
    __syncthreads();
    for (int p = tid; p < cnt; p += 256) {
        const nfloat4 r = recs[j0 + p];
        srecs[p] = r;
        atomicAdd(&cnt64[__float_as_int(r.w) - node0], 1);
    }
    __syncthreads();
    if (tid < 64) {
        const int v = cnt64[tid];
        int x = v;
        #pragma unroll
        for (int k = 1; k < 64; k <<= 1) { int t = __shfl_up(x, k, 64); if (tid >= k) x += t; }
        run64[tid] = x - v;
        if (node0 + tid < N_NODES) {
            nodeoff[node0 + tid] = j0 + x - v;
            nodeend[node0 + tid] = j0 + x;
        }
    }
    __syncthreads();
    for (int p = tid; p < cnt; p += 256) {
        const int dl = __float_as_int(srecs[p].w) - node0;
        const int rk = atomicAdd(&run64[dl], 1);
        recs[j0 + rk] = srecs[p];
    }
}

__global__ __launch_bounds__(256) void gather_fix(const float* __restrict__ state,
                                                  const int* __restrict__ nodeoff,
                                                  const int* __restrict__ nodeend,
                                                  const int* __restrict__ gcur,
                                                  const nfloat4* __restrict__ recs,
                                                  float* __restrict__ out,
                                                  const int csg) {
    const int n = blockIdx.x * 4 + (threadIdx.x >> 6);
    const int d = threadIdx.x & 63;
    if (n >= N_NODES) return;
    const size_t plane = (size_t)N_NODES * D_FEAT;

    const int j0 = nodeoff[n];
    float a0 = 0.f, a1 = 0.f;
    if (j0 < 0) {
        const int b = n >> BKT_SHIFT;
        const int jb0 = b * csg, jb1 = jb0 + min(gcur[b], csg);
        for (int j = jb0; j < jb1; ++j) {
            const nfloat4 r = recs[j];
            if (__float_as_int(r.w) == n) {
                const int s = __float_as_int(r.x);
                a0 += state[(size_t)s * D_FEAT + d]         * r.y;
                a1 += state[plane + (size_t)s * D_FEAT + d] * r.z;
            }
        }
    } else {
        const int j1 = nodeend[n];
        for (int base = j0; base < j1; base += 64) {
            const int cnt = min(64, j1 - base);
            nfloat4 r = (nfloat4)(0.f);
            if (d < cnt) r = __builtin_nontemporal_load(recs + base + d);
            for (int j = 0; j < cnt; j += 16) {
                int   s[16]; float wx[16], wy[16], v0[16], v1[16];
                #pragma unroll
                for (int u = 0; u < 16; ++u) {
                    s[u]  = __shfl(__float_as_int(r.x), j + u, 64);
                    wx[u] = __shfl(r.y, j + u, 64);
                    wy[u] = __shfl(r.z, j + u, 64);
                }
                #pragma unroll
                for (int u = 0; u < 16; ++u) {
                    v0[u] = state[(size_t)s[u] * D_FEAT + d];
                    v1[u] = state[plane + (size_t)s[u] * D_FEAT + d];
                }
                #pragma unroll
                for (int u = 0; u < 16; ++u) {
                    a0 += v0[u] * wx[u];
                    a1 += v1[u] * wy[u];
                }
            }
        }
    }
    __builtin_nontemporal_store(a0, out + (size_t)n * D_FEAT + d);
    __builtin_nontemporal_store(a1, out + plane + (size_t)n * D_FEAT + d);
}

// ---------------- fallback (ws too small): round-1 atomic kernel ----------------
__global__ __launch_bounds__(256) void scatter_add_kernel(
    const float* __restrict__ state, const int* __restrict__ edge_index,
    const float* __restrict__ weight, float* __restrict__ out) {
    const int e = blockIdx.x * 4 + (threadIdx.x >> 6);
    const int d = threadIdx.x & 63;
    if (e >= N_EDGES) return;
    const int src = edge_index[e];
    const int dst = edge_index[N_EDGES + e];
    const float w0 = weight[e * 2 + 0];
    const float w1 = weight[e * 2 + 1];
    const size_t plane = (size_t)N_NODES * D_FEAT;
    const float s0 = state[(size_t)src * D_FEAT + d];
    const float s1 = state[plane + (size_t)src * D_FEAT + d];
    atomicAdd(out + (size_t)dst * D_FEAT + d,         s0 * w0);
    atomicAdd(out + plane + (size_t)dst * D_FEAT + d, s1 * w1);
}

extern "C" void kernel_launch(void* const* d_in, const int* in_sizes, int n_in,
                              void* d_out, int out_size, void* d_ws, size_t ws_size,
                              hipStream_t stream) {
    const float* state      = (const float*)d_in[0];
    const int*   edge_index = (const int*)d_in[1];
    const float* weight     = (const float*)d_in[2];
    float*       out        = (float*)d_out;

    // bf16/8B-path capacity
    long long availB = (long long)ws_size - WSB_RECS;
    int csgB = 0;
    if (availB > 0) {
        long long c = availB / ((long long)NB * 8);
        csgB = (int)(c > CAP ? CAP : c);
    }
    // f32-path capacity (R18)
    long long availF = (long long)ws_size - WSF_RECS;
    int csgF = 0;
    if (availF > 0) {
        long long c = availF / ((long long)NB * 16);
        csgF = (int)(c > CAP ? CAP : c);
    }

    if (csgB >= CSG_MIN) {
        // ---- bf16/8B fused path ----
        char* ws = (char*)d_ws;
        int*          gcur    = (int*)(ws + WSB_GCUR);
        int*          nodeoff = (int*)(ws + WSB_NOFF);
        int*          nodeend = (int*)(ws + WSB_NEND);
        unsigned int* sbf     = (unsigned int*)(ws + WSB_SBF);
        nuint2*       recs8   = (nuint2*)(ws + WSB_RECS);

        (void)hipMemsetAsync(gcur, 0, NB * sizeof(int), stream);
        hipLaunchKernelGGL(build_fused, dim3(NCHUNK_SCAT + NPACK), dim3(256), 0, stream,
                           edge_index, weight, state, gcur, recs8, sbf, csgB);
        hipLaunchKernelGGL(sort_fix8, dim3(NB), dim3(256), 0, stream,
                           gcur, recs8, nodeoff, nodeend, csgB);
        hipLaunchKernelGGL(gather_bf8, dim3((N_NODES + 3) / 4), dim3(256), 0, stream,
                           sbf, nodeoff, nodeend, gcur, recs8, out, csgB);
    } else if (csgF >= CSG_MIN) {
        // ---- f32 fixed-segment path (R18, proven 97 us) ----
        char* ws = (char*)d_ws;
        int*     gcur    = (int*)(ws + WSF_GCUR);
        int*     nodeoff = (int*)(ws + WSF_NOFF);
        int*     nodeend = (int*)(ws + WSF_NEND);
        nfloat4* recs    = (nfloat4*)(ws + WSF_RECS);

        (void)hipMemsetAsync(gcur, 0, NB * sizeof(int), stream);
        hipLaunchKernelGGL(scatter_fix, dim3(NCHUNK_SCAT), dim3(256), 0, stream,
                           edge_index, weight, gcur, recs, csgF);
        hipLaunchKernelGGL(sort_fix, dim3(NB), dim3(256), 0, stream,
                           gcur, recs, nodeoff, nodeend, csgF);
        hipLaunchKernelGGL(gather_fix, dim3((N_NODES + 3) / 4), dim3(256), 0, stream,
                           state, nodeoff, nodeend, gcur, recs, out, csgF);
    } else {
        (void)hipMemsetAsync(out, 0, (size_t)out_size * sizeof(float), stream);
        hipLaunchKernelGGL(scatter_add_kernel, dim3((N_EDGES + 3) / 4), dim3(256), 0, stream,
                           state, edge_index, weight, out);
    }
}

// Round 22
// 75.539 us; speedup vs baseline: 1.0372x; 1.0372x over previous
//
#include <hip/hip_runtime.h>

#define N_NODES 50000
#define N_EDGES 800000
#define D_FEAT  64
#define TOTALSD (N_NODES * D_FEAT)       // 3,200,000 elems per plane

#define BKT_SHIFT 6
#define NB  782                          // ceil(50000/64) buckets of 64 nodes
#define C_SCAT 4096
#define NCHUNK_SCAT ((N_EDGES + C_SCAT - 1) / C_SCAT)   // 196
#define NPACK ((TOTALSD + 4095) / 4096)                 // 782 pack WGs
#define CAP 2048

typedef float nfloat2 __attribute__((ext_vector_type(2)));
typedef float nfloat4 __attribute__((ext_vector_type(4)));
typedef unsigned int nuint2 __attribute__((ext_vector_type(2)));

// ---------------- bf16/8B workspace layout (bytes) ----------------
// gcur    : NB ints      @ 0
// nodeoff : N+1 ints     @ 4096
// nodeend : N ints       @ 204160
// sbf     : N*D uints    @ 404224    (packed state bf16x2, 12.8 MB)
// recs8   : NB*csg nuint2 @ 13204224 ({src<<6|dl, w0|w1<<16 bf16x2}, <=12.8 MB)
#define WSB_GCUR  0
#define WSB_NOFF  4096
#define WSB_NEND  204160
#define WSB_SBF   404224
#define WSB_RECS  13204224
#define CSG_MIN   1216                   // >= 6 sigma above realized max bucket

// ---------------- f32 fixed-segment layout (R18 proven fallback) ----------------
#define WSF_GCUR  0
#define WSF_NOFF  4096
#define WSF_NEND  204160
#define WSF_RECS  404224

// ---- exclusive scan of NB(=782) ints with 256 threads (ends with sync) ----
__device__ __forceinline__ void scan_nb(const int* __restrict__ cnt,
                                        int* __restrict__ off) {
    __shared__ int wsum2[4];
    const int tid = threadIdx.x, lane = tid & 63, wid = tid >> 6;
    const int i0 = tid * 4;
    int v[4]; int s = 0;
    #pragma unroll
    for (int j = 0; j < 4; ++j) { v[j] = (i0 + j < NB) ? cnt[i0 + j] : 0; s += v[j]; }
    int x = s;
    #pragma unroll
    for (int k = 1; k < 64; k <<= 1) { int t = __shfl_up(x, k, 64); if (lane >= k) x += t; }
    if (lane == 63) wsum2[wid] = x;
    __syncthreads();
    int wpre = 0;
    for (int k = 0; k < wid; ++k) wpre += wsum2[k];
    int pre = wpre + x - s;
    #pragma unroll
    for (int j = 0; j < 4; ++j) { if (i0 + j < NB) off[i0 + j] = pre; pre += v[j]; }
    if (tid == 255) off[NB] = pre;
    __syncthreads();
}

__device__ __forceinline__ unsigned int bf16rne(float f) {
    unsigned int u = __float_as_uint(f);
    return (u + 0x7fffu + ((u >> 16) & 1u)) >> 16;
}

// ======== fused build: blocks [0,196) scatter 8B records; [196,978) pack state ========
__global__ __launch_bounds__(256) void build_fused(const int* __restrict__ ei,
                                                   const float* __restrict__ w,
                                                   const float* __restrict__ state,
                                                   int* __restrict__ gcur,
                                                   nuint2* __restrict__ recs8,
                                                   unsigned int* __restrict__ sbf,
                                                   const int csg) {
    __shared__ int cnt[NB];
    __shared__ int off[NB + 1];
    __shared__ int run[NB];
    __shared__ int gpos[NB];
    __shared__ int seid[C_SCAT];
    const int tid = threadIdx.x;

    if (blockIdx.x >= NCHUNK_SCAT) {
        // ---- pack branch: 4096 elems per WG, uint4 stores ----
        const int base0 = (blockIdx.x - NCHUNK_SCAT) * 4096;
        #pragma unroll
        for (int k = 0; k < 4; ++k) {
            const int idx = base0 + k * 1024 + tid * 4;
            if (idx < TOTALSD) {
                const nfloat4 a = *(const nfloat4*)(state + idx);
                const nfloat4 b = *(const nfloat4*)(state + (size_t)TOTALSD + idx);
                uint4 o;
                o.x = bf16rne(a.x) | (bf16rne(b.x) << 16);
                o.y = bf16rne(a.y) | (bf16rne(b.y) << 16);
                o.z = bf16rne(a.z) | (bf16rne(b.z) << 16);
                o.w = bf16rne(a.w) | (bf16rne(b.w) << 16);
                *(uint4*)(sbf + idx) = o;
            }
        }
        return;
    }

    // ---- scatter branch (control flow identical to validated R18 scatter_fix) ----
    const int base = blockIdx.x * C_SCAT;
    const int csz  = min(C_SCAT, N_EDGES - base);

    for (int i = tid; i < NB; i += 256) cnt[i] = 0;
    __syncthreads();
    for (int k = 0; k < C_SCAT / 256; ++k) {
        const int p = k * 256 + tid;
        if (p < csz) atomicAdd(&cnt[ei[N_EDGES + base + p] >> BKT_SHIFT], 1);
    }
    __syncthreads();
    scan_nb(cnt, off);
    for (int i = tid; i < NB; i += 256) run[i] = off[i];
    __syncthreads();
    for (int i = tid; i < NB; i += 256) {
        const int c = off[i + 1] - off[i];
        gpos[i] = c ? (i * csg + atomicAdd(&gcur[i], c) - off[i]) : 0;
    }
    for (int k = 0; k < C_SCAT / 256; ++k) {
        const int p = k * 256 + tid;
        if (p < csz) {
            const int r = atomicAdd(&run[ei[N_EDGES + base + p] >> BKT_SHIFT], 1);
            seid[r] = p;
        }
    }
    __syncthreads();
    for (int k = 0; k < C_SCAT / 256; ++k) {
        const int p = k * 256 + tid;
        if (p < csz) {
            const int e   = base + seid[p];
            const int dst = ei[N_EDGES + e];
            const int b   = dst >> BKT_SHIFT;
            const int slot = gpos[b] + p;
            if (slot - b * csg < csg) {                   // overflow guard
                const nfloat2 wv = *(const nfloat2*)(w + 2 * (size_t)e);
                nuint2 rec;
                rec.x = ((unsigned int)ei[e] << 6) | (unsigned int)(dst & 63);
                rec.y = bf16rne(wv.x) | (bf16rne(wv.y) << 16);
                recs8[(size_t)slot] = rec;
            }
        }
    }
}

// sort: per-bucket in-place node sort of 8B records; emits [nodeoff, nodeend)
__global__ __launch_bounds__(256) void sort_fix8(const int* __restrict__ gcur,
                                                 nuint2* __restrict__ recs8,
                                                 int* __restrict__ nodeoff,
                                                 int* __restrict__ nodeend,
                                                 const int csg) {
    __shared__ nuint2 srecs[CAP];        // 16 KB
    __shared__ int cnt64[64];
    __shared__ int run64[64];
    const int tid = threadIdx.x;
    const int b = blockIdx.x;
    const int node0 = b << BKT_SHIFT;
    const int j0 = b * csg;
    const int cnt = min(gcur[b], csg);

    if (gcur[b] > csg) {                 // unreachable for this input; stay defined
        if (tid < 64 && node0 + tid < N_NODES) {
            nodeoff[node0 + tid] = -1;
            nodeend[node0 + tid] = -1;
        }
        return;
    }
    if (tid < 64) cnt64[tid] = 0;
    __syncthreads();
    for (int p = tid; p < cnt; p += 256) {
        const nuint2 r = recs8[j0 + p];
        srecs[p] = r;
        atomicAdd(&cnt64[r.x & 63u], 1);
    }
    __syncthreads();
    if (tid < 64) {
        const int v = cnt64[tid];
        int x = v;
        #pragma unroll
        for (int k = 1; k < 64; k <<= 1) { int t = __shfl_up(x, k, 64); if (tid >= k) x += t; }
        run64[tid] = x - v;
        if (node0 + tid < N_NODES) {
            nodeoff[node0 + tid] = j0 + x - v;
            nodeend[node0 + tid] = j0 + x;
        }
    }
    __syncthreads();
    for (int p = tid; p < cnt; p += 256) {
        const nuint2 r = srecs[p];
        const int rk = atomicAdd(&run64[r.x & 63u], 1);
        recs8[j0 + rk] = r;
    }
}

// gather: packed bf16 state, 8B records, one wave/node, x16 unroll, zero-pad
__global__ __launch_bounds__(256) void gather_bf8(const unsigned int* __restrict__ sbf,
                                                  const int* __restrict__ nodeoff,
                                                  const int* __restrict__ nodeend,
                                                  const int* __restrict__ gcur,
                                                  const nuint2* __restrict__ recs8,
                                                  float* __restrict__ out,
                                                  const int csg) {
    const int n = blockIdx.x * 4 + (threadIdx.x >> 6);
    const int d = threadIdx.x & 63;
    if (n >= N_NODES) return;
    const size_t plane = (size_t)N_NODES * D_FEAT;

    const int j0 = nodeoff[n];
    float a0 = 0.f, a1 = 0.f;
    if (j0 < 0) {
        // oversized-bucket slow path (unreachable): filter-scan the segment
        const int b = n >> BKT_SHIFT;
        const int node0 = b << BKT_SHIFT;
        const int jb0 = b * csg, jb1 = jb0 + min(gcur[b], csg);
        for (int j = jb0; j < jb1; ++j) {
            const nuint2 r = recs8[j];
            if ((int)(node0 + (r.x & 63u)) == n) {
                const int s = (int)(r.x >> 6);
                const unsigned int v = sbf[(size_t)s * D_FEAT + d];
                a0 += __uint_as_float(v << 16)         * __uint_as_float(r.y << 16);
                a1 += __uint_as_float(v & 0xffff0000u) * __uint_as_float(r.y & 0xffff0000u);
            }
        }
    } else {
        const int j1 = nodeend[n];
        for (int base = j0; base < j1; base += 64) {
            const int cnt = min(64, j1 - base);
            nuint2 r; r.x = 0u; r.y = 0u;                 // zero-pad: s=0, w=0
            if (d < cnt) r = __builtin_nontemporal_load(recs8 + base + d);

            for (int j = 0; j < cnt; j += 16) {
                int s[16]; unsigned int wb[16], v[16];
                #pragma unroll
                for (int u = 0; u < 16; ++u) {
                    s[u]  = __shfl((int)r.x, j + u, 64) >> 6;
                    wb[u] = (unsigned int)__shfl((int)r.y, j + u, 64);
                }
                #pragma unroll
                for (int u = 0; u < 16; ++u)
                    v[u] = sbf[(size_t)s[u] * D_FEAT + d];    // cacheable (reuse!)
                #pragma unroll
                for (int u = 0; u < 16; ++u) {
                    a0 += __uint_as_float(v[u] << 16)         * __uint_as_float(wb[u] << 16);
                    a1 += __uint_as_float(v[u] & 0xffff0000u) * __uint_as_float(wb[u] & 0xffff0000u);
                }
            }
        }
    }
    __builtin_nontemporal_store(a0, out + (size_t)n * D_FEAT + d);
    __builtin_nontemporal_store(a1, out + plane + (size_t)n * D_FEAT + d);
}

// ================= f32 fixed-segment pipeline (R18 proven fallback) =================
__global__ __launch_bounds__(256) void scatter_fix(const int* __restrict__ ei,
                                                   const float* __restrict__ w,
                                                   int* __restrict__ gcur,
                                                   nfloat4* __restrict__ recs,
                                                   const int csg) {
    __shared__ int cnt[NB];
    __shared__ int off[NB + 1];
    __shared__ int run[NB];
    __shared__ int gpos[NB];
    __shared__ int seid[C_SCAT];
    const int tid  = threadIdx.x;
    const int base = blockIdx.x * C_SCAT;
    const int csz  = min(C_SCAT, N_EDGES - base);

    for (int i = tid; i < NB; i += 256) cnt[i] = 0;
    __syncthreads();
    for (int k = 0; k < C_SCAT / 256; ++k) {
        const int p = k * 256 + tid;
        if (p < csz) atomicAdd(&cnt[ei[N_EDGES + base + p] >> BKT_SHIFT], 1);
    }
    __syncthreads();
    scan_nb(cnt, off);
    for (int i = tid; i < NB; i += 256) run[i] = off[i];
    __syncthreads();
    for (int i = tid; i < NB; i += 256) {
        const int c = off[i + 1] - off[i];
        gpos[i] = c ? (i * csg + atomicAdd(&gcur[i], c) - off[i]) : 0;
    }
    for (int k = 0; k < C_SCAT / 256; ++k) {
        const int p = k * 256 + tid;
        if (p < csz) {
            const int r = atomicAdd(&run[ei[N_EDGES + base + p] >> BKT_SHIFT], 1);
            seid[r] = p;
        }
    }
    __syncthreads();
    for (int k = 0; k < C_SCAT / 256; ++k) {
        const int p = k * 256 + tid;
        if (p < csz) {
            const int e   = base + seid[p];
            const int dst = ei[N_EDGES + e];
            const int b   = dst >> BKT_SHIFT;
            const int slot = gpos[b] + p;
            if (slot - b * csg < csg) {
                const nfloat2 wv = *(const nfloat2*)(w + 2 * (size_t)e);
                nfloat4 rec;
                rec.x = __int_as_float(ei[e]);
                rec.y = wv.x;
                rec.z = wv.y;
                rec.w = __int_as_float(dst);
                recs[(size_t)slot] = rec;
            }
        }
    }
}

__global__ __launch_bounds__(256) void sort_fix(const int* __restrict__ gcur,
                                                nfloat4* __restrict__ recs,
                                                int* __restrict__ nodeoff,
                                                int* __restrict__ nodeend,
                                                const int csg) {
    __shared__ nfloat4 srecs[CAP];
    __shared__ int cnt64[64];
    __shared__ int run64[64];
    const int tid = threadIdx.x;
    const int b = blockIdx.x;
    const int node0 = b << BKT_SHIFT;
    const int j0 = b * csg;
    const int cnt = min(gcur[b], csg);

    if (gcur[b] > csg) {
        if (tid < 64 && node0 + tid < N_NODES) {
            nodeoff[node0 + tid] = -1;
            nodeend[node0 + tid] = -1;
        }
        return;
    }
    if (tid < 64) cnt64[tid] = 0;
    __syncthreads();
    for (int p = tid; p < cnt; p += 256) {
        const nfloat4 r = recs[j0 + p];
        srecs[p] = r;
        atomicAdd(&cnt64[__float_as_int(r.w) - node0], 1);
    }
    __syncthreads();
    if (tid < 64) {
        const int v = cnt64[tid];
        int x = v;
        #pragma unroll
        for (int k = 1; k < 64; k <<= 1) { int t = __shfl_up(x, k, 64); if (tid >= k) x += t; }
        run64[tid] = x - v;
        if (node0 + tid < N_NODES) {
            nodeoff[node0 + tid] = j0 + x - v;
            nodeend[node0 + tid] = j0 + x;
        }
    }
    __syncthreads();
    for (int p = tid; p < cnt; p += 256) {
        const int dl = __float_as_int(srecs[p].w) - node0;
        const int rk = atomicAdd(&run64[dl], 1);
        recs[j0 + rk] = srecs[p];
    }
}

__global__ __launch_bounds__(256) void gather_fix(const float* __restrict__ state,
                                                  const int* __restrict__ nodeoff,
                                                  const int* __restrict__ nodeend,
                                                  const int* __restrict__ gcur,
                                                  const nfloat4* __restrict__ recs,
                                                  float* __restrict__ out,
                                                  const int csg) {
    const int n = blockIdx.x * 4 + (threadIdx.x >> 6);
    const int d = threadIdx.x & 63;
    if (n >= N_NODES) return;
    const size_t plane = (size_t)N_NODES * D_FEAT;

    const int j0 = nodeoff[n];
    float a0 = 0.f, a1 = 0.f;
    if (j0 < 0) {
        const int b = n >> BKT_SHIFT;
        const int jb0 = b * csg, jb1 = jb0 + min(gcur[b], csg);
        for (int j = jb0; j < jb1; ++j) {
            const nfloat4 r = recs[j];
            if (__float_as_int(r.w) == n) {
                const int s = __float_as_int(r.x);
                a0 += state[(size_t)s * D_FEAT + d]         * r.y;
                a1 += state[plane + (size_t)s * D_FEAT + d] * r.z;
            }
        }
    } else {
        const int j1 = nodeend[n];
        for (int base = j0; base < j1; base += 64) {
            const int cnt = min(64, j1 - base);
            nfloat4 r = (nfloat4)(0.f);
            if (d < cnt) r = __builtin_nontemporal_load(recs + base + d);
            for (int j = 0; j < cnt; j += 16) {
                int   s[16]; float wx[16], wy[16], v0[16], v1[16];
                #pragma unroll
                for (int u = 0; u < 16; ++u) {
                    s[u]  = __shfl(__float_as_int(r.x), j + u, 64);
                    wx[u] = __shfl(r.y, j + u, 64);
                    wy[u] = __shfl(r.z, j + u, 64);
                }
                #pragma unroll
                for (int u = 0; u < 16; ++u) {
                    v0[u] = state[(size_t)s[u] * D_FEAT + d];
                    v1[u] = state[plane + (size_t)s[u] * D_FEAT + d];
                }
                #pragma unroll
                for (int u = 0; u < 16; ++u) {
                    a0 += v0[u] * wx[u];
                    a1 += v1[u] * wy[u];
                }
            }
        }
    }
    __builtin_nontemporal_store(a0, out + (size_t)n * D_FEAT + d);
    __builtin_nontemporal_store(a1, out + plane + (size_t)n * D_FEAT + d);
}

// ---------------- fallback (ws too small): round-1 atomic kernel ----------------
__global__ __launch_bounds__(256) void scatter_add_kernel(
    const float* __restrict__ state, const int* __restrict__ edge_index,
    const float* __restrict__ weight, float* __restrict__ out) {
    const int e = blockIdx.x * 4 + (threadIdx.x >> 6);
    const int d = threadIdx.x & 63;
    if (e >= N_EDGES) return;
    const int src = edge_index[e];
    const int dst = edge_index[N_EDGES + e];
    const float w0 = weight[e * 2 + 0];
    const float w1 = weight[e * 2 + 1];
    const size_t plane = (size_t)N_NODES * D_FEAT;
    const float s0 = state[(size_t)src * D_FEAT + d];
    const float s1 = state[plane + (size_t)src * D_FEAT + d];
    atomicAdd(out + (size_t)dst * D_FEAT + d,         s0 * w0);
    atomicAdd(out + plane + (size_t)dst * D_FEAT + d, s1 * w1);
}

extern "C" void kernel_launch(void* const* d_in, const int* in_sizes, int n_in,
                              void* d_out, int out_size, void* d_ws, size_t ws_size,
                              hipStream_t stream) {
    const float* state      = (const float*)d_in[0];
    const int*   edge_index = (const int*)d_in[1];
    const float* weight     = (const float*)d_in[2];
    float*       out        = (float*)d_out;

    // bf16/8B-path capacity
    long long availB = (long long)ws_size - WSB_RECS;
    int csgB = 0;
    if (availB > 0) {
        long long c = availB / ((long long)NB * 8);
        csgB = (int)(c > CAP ? CAP : c);
    }
    // f32-path capacity (R18)
    long long availF = (long long)ws_size - WSF_RECS;
    int csgF = 0;
    if (availF > 0) {
        long long c = availF / ((long long)NB * 16);
        csgF = (int)(c > CAP ? CAP : c);
    }

    if (csgB >= CSG_MIN) {
        // ---- bf16/8B fused path ----
        char* ws = (char*)d_ws;
        int*          gcur    = (int*)(ws + WSB_GCUR);
        int*          nodeoff = (int*)(ws + WSB_NOFF);
        int*          nodeend = (int*)(ws + WSB_NEND);
        unsigned int* sbf     = (unsigned int*)(ws + WSB_SBF);
        nuint2*       recs8   = (nuint2*)(ws + WSB_RECS);

        (void)hipMemsetAsync(gcur, 0, NB * sizeof(int), stream);
        hipLaunchKernelGGL(build_fused, dim3(NCHUNK_SCAT + NPACK), dim3(256), 0, stream,
                           edge_index, weight, state, gcur, recs8, sbf, csgB);
        hipLaunchKernelGGL(sort_fix8, dim3(NB), dim3(256), 0, stream,
                           gcur, recs8, nodeoff, nodeend, csgB);
        hipLaunchKernelGGL(gather_bf8, dim3((N_NODES + 3) / 4), dim3(256), 0, stream,
                           sbf, nodeoff, nodeend, gcur, recs8, out, csgB);
    } else if (csgF >= CSG_MIN) {
        // ---- f32 fixed-segment path (R18, proven 97 us) ----
        char* ws = (char*)d_ws;
        int*     gcur    = (int*)(ws + WSF_GCUR);
        int*     nodeoff = (int*)(ws + WSF_NOFF);
        int*     nodeend = (int*)(ws + WSF_NEND);
        nfloat4* recs    = (nfloat4*)(ws + WSF_RECS);

        (void)hipMemsetAsync(gcur, 0, NB * sizeof(int), stream);
        hipLaunchKernelGGL(scatter_fix, dim3(NCHUNK_SCAT), dim3(256), 0, stream,
                           edge_index, weight, gcur, recs, csgF);
        hipLaunchKernelGGL(sort_fix, dim3(NB), dim3(256), 0, stream,
                           gcur, recs, nodeoff, nodeend, csgF);
        hipLaunchKernelGGL(gather_fix, dim3((N_NODES + 3) / 4), dim3(256), 0, stream,
                           state, nodeoff, nodeend, gcur, recs, out, csgF);
    } else {
        (void)hipMemsetAsync(out, 0, (size_t)out_size * sizeof(float), stream);
        hipLaunchKernelGGL(scatter_add_kernel, dim3((N_EDGES + 3) / 4), dim3(256), 0, stream,
                           state, edge_index, weight, out);
    }
}